// Round 5
// baseline (952.690 us; speedup 1.0000x reference)
//
#include <hip/hip_runtime.h>
#include <cstdint>
#include <cstddef>

// ---------------------------------------------------------------------------
// MaxK-GIN: h=relu(x@W_in+b); 2x { h=h@W+b; maxk16; neigh=sum_in(h_sparse);
//           h=(1+eps)*h_sparse+neigh }; out = h@W_out+b_out
// R5: persistent grid-stride for gather/hist/fill (test dispatch-rate bound);
// GEMM grids 512 vs 1024 A/B on the two identical layer GEMMs.
// ---------------------------------------------------------------------------

typedef __attribute__((ext_vector_type(8))) short bf16x8;
typedef __attribute__((ext_vector_type(4))) float f32x4;

__device__ __forceinline__ unsigned rne_bf16(float v) {
  unsigned u = __float_as_uint(v);
  return (u + 0x7fffu + ((u >> 16) & 1u)) >> 16;
}

// ---------------- fused W^T build: all 4 weights -> hi/lo bf16 --------------
__global__ __launch_bounds__(256) void wt_build_all_kernel(
    const float* __restrict__ W_in, const float* __restrict__ W_lin,
    const float* __restrict__ W_out, short* __restrict__ out) {
  const int i = blockIdx.x * 256 + threadIdx.x;
  if (i >= 57344) return;
  const float* W;
  int nout, local;
  short* H;
  if (i < 16384) {
    W = W_in; nout = 128; local = i; H = out;
  } else if (i < 32768) {
    W = W_lin; nout = 128; local = i - 16384; H = out + 32768;
  } else if (i < 49152) {
    W = W_lin + 16384; nout = 128; local = i - 32768; H = out + 65536;
  } else {
    W = W_out; nout = 64; local = i - 49152; H = out + 98304;
  }
  const int nn = local >> 7, k = local & 127;
  const float v = W[k * nout + nn];
  const unsigned hb = rne_bf16(v);
  const float hf = __uint_as_float(hb << 16);
  const unsigned lb = rne_bf16(v - hf);
  H[local] = (short)hb;
  H[local + nout * 128] = (short)lb;
}

// ---------------- MFMA GEMM: Y = X[.,128] @ W + bias (opt relu) -------------
template <int NOUT, bool RELU>
__global__ __launch_bounds__(256, 2) void mfma_gemm_kernel(
    const float* __restrict__ X, const short* __restrict__ WtH,
    const short* __restrict__ WtL, const float* __restrict__ bias,
    float* __restrict__ Y, int nrows, int ntiles) {
  constexpr int NT = NOUT / 16;
  constexpr int LDB = 128 * 2 + 16;  // bytes per row, +16B pad (2-way, free)
  constexpr int PLANE = NOUT * LDB;
  __shared__ char lds[2 * PLANE];

  const int tid = threadIdx.x;
  for (int u = tid; u < 2 * NOUT * 16; u += 256) {
    const int plane = u / (NOUT * 16);
    const int v = u % (NOUT * 16);
    const int nrow = v >> 4, seg = v & 15;
    const short* src = plane ? WtL : WtH;
    const float4 d = *(const float4*)&src[nrow * 128 + seg * 8];
    *(float4*)&lds[plane * PLANE + nrow * LDB + seg * 16] = d;
  }
  __syncthreads();  // only barrier; LDS read-only afterwards

  const int lane = tid & 63;
  const int wv = tid >> 6;
  const int li = lane & 15;
  const int kg = lane >> 4;

  float bv[NT];
#pragma unroll
  for (int t = 0; t < NT; ++t) bv[t] = bias[t * 16 + li];

  for (int tile = blockIdx.x; tile < ntiles; tile += gridDim.x) {
    const int row = tile * 64 + wv * 16 + li;
    const int rowc = (row < nrows) ? row : (nrows - 1);
    const float* xrow = X + (size_t)rowc * 128;

    f32x4 acc[NT];
#pragma unroll
    for (int t = 0; t < NT; ++t) acc[t] = (f32x4){0.f, 0.f, 0.f, 0.f};

#pragma unroll
    for (int c = 0; c < 4; ++c) {
      const float4 p0 = *(const float4*)&xrow[c * 32 + kg * 8];
      const float4 p1 = *(const float4*)&xrow[c * 32 + kg * 8 + 4];
      float f[8] = {p0.x, p0.y, p0.z, p0.w, p1.x, p1.y, p1.z, p1.w};
      bf16x8 ah, al;
#pragma unroll
      for (int e = 0; e < 8; ++e) {
        const unsigned hb = rne_bf16(f[e]);
        const float hf = __uint_as_float(hb << 16);
        const unsigned lb = rne_bf16(f[e] - hf);
        ah[e] = (short)hb;
        al[e] = (short)lb;
      }
      const int kb = c * 64 + kg * 16;
#pragma unroll
      for (int t = 0; t < NT; ++t) {
        const int boff = (t * 16 + li) * LDB + kb;
        const bf16x8 bh = *(const bf16x8*)&lds[boff];
        const bf16x8 bl = *(const bf16x8*)&lds[PLANE + boff];
        acc[t] = __builtin_amdgcn_mfma_f32_16x16x32_bf16(al, bh, acc[t], 0, 0, 0);
        acc[t] = __builtin_amdgcn_mfma_f32_16x16x32_bf16(ah, bl, acc[t], 0, 0, 0);
        acc[t] = __builtin_amdgcn_mfma_f32_16x16x32_bf16(ah, bh, acc[t], 0, 0, 0);
      }
    }

    const int orow = tile * 64 + wv * 16 + kg * 4;
#pragma unroll
    for (int t = 0; t < NT; ++t) {
      const int col = t * 16 + li;
#pragma unroll
      for (int r = 0; r < 4; ++r) {
        const int rr = orow + r;
        if (rr < nrows) {
          float o = acc[t][r] + bv[t];
          if (RELU) o = fmaxf(o, 0.f);
          Y[(size_t)rr * NOUT + col] = o;
        }
      }
    }
  }
}

// ---------------- MaxK: top-16 of 128 per row -> packed (val, idx) ----------
__global__ __launch_bounds__(256) void maxk_kernel(
    const float* __restrict__ T, float2* __restrict__ pairs, int nrows) {
  const int lane = threadIdx.x & 63;
  const int wid = threadIdx.x >> 6;

  for (int row = blockIdx.x * 4 + wid; row < nrows; row += gridDim.x * 4) {
    float v0 = T[(size_t)row * 128 + lane];
    float v1 = T[(size_t)row * 128 + 64 + lane];

#pragma unroll
    for (int it = 0; it < 16; ++it) {
      float m = fmaxf(v0, v1);
#pragma unroll
      for (int off = 32; off; off >>= 1) m = fmaxf(m, __shfl_xor(m, off));
      const unsigned long long b0 = __ballot(v0 == m);
      int sel;
      if (b0) {
        sel = __ffsll(b0) - 1;
        if (lane == sel) v0 = -INFINITY;
      } else {
        const unsigned long long b1 = __ballot(v1 == m);
        sel = __ffsll(b1) - 1;
        if (lane == sel) v1 = -INFINITY;
        sel += 64;
      }
      if (lane == 0) {
        pairs[(size_t)row * 16 + it] = make_float2(m, __int_as_float(sel));
      }
    }
  }
}

// ---------------- CSR build (persistent grids) ------------------------------
__global__ __launch_bounds__(256) void hist_kernel(const int* __restrict__ dst,
                                                   int* __restrict__ deg,
                                                   int E) {
  const int stride = gridDim.x * 256;
  for (int e = blockIdx.x * 256 + threadIdx.x; e < E; e += stride)
    atomicAdd(&deg[dst[e]], 1);
}

__global__ __launch_bounds__(256) void scan1_kernel(
    const int* __restrict__ deg, int* __restrict__ out,
    int* __restrict__ bsums, int n) {
  __shared__ int wsum[4];
  const int t = threadIdx.x;
  const int base = blockIdx.x * 1024 + t * 4;
  int d0 = 0, d1 = 0, d2 = 0, d3 = 0;
  if (base + 0 < n) d0 = deg[base + 0];
  if (base + 1 < n) d1 = deg[base + 1];
  if (base + 2 < n) d2 = deg[base + 2];
  if (base + 3 < n) d3 = deg[base + 3];
  const int s = d0 + d1 + d2 + d3;
  const int lane = t & 63, wid = t >> 6;
  int incl = s;
#pragma unroll
  for (int off = 1; off < 64; off <<= 1) {
    int u = __shfl_up(incl, off);
    if (lane >= off) incl += u;
  }
  if (lane == 63) wsum[wid] = incl;
  __syncthreads();
  int woff = 0;
  for (int w = 0; w < wid; ++w) woff += wsum[w];
  const int excl = woff + incl - s;
  if (base + 0 < n) out[base + 0] = excl;
  if (base + 1 < n) out[base + 1] = excl + d0;
  if (base + 2 < n) out[base + 2] = excl + d0 + d1;
  if (base + 3 < n) out[base + 3] = excl + d0 + d1 + d2;
  if (t == 255) bsums[blockIdx.x] = woff + incl;
}

__global__ __launch_bounds__(64) void scan2_kernel(int* __restrict__ bsums,
                                                   int nb) {
  const int lane = threadIdx.x;
  const int a = (lane < nb) ? bsums[lane] : 0;
  const int b = (lane + 64 < nb) ? bsums[lane + 64] : 0;
  int ia = a, ib = b;
#pragma unroll
  for (int off = 1; off < 64; off <<= 1) {
    const int ta = __shfl_up(ia, off);
    const int tb = __shfl_up(ib, off);
    if (lane >= off) { ia += ta; ib += tb; }
  }
  const int totA = __shfl(ia, 63);
  if (lane < nb) bsums[lane] = ia - a;
  if (lane + 64 < nb) bsums[lane + 64] = totA + ib - b;
}

__global__ __launch_bounds__(256) void scan3_kernel(
    int* __restrict__ rs, int* __restrict__ cursor,
    const int* __restrict__ bsums, int n, int E) {
  const int i = blockIdx.x * 256 + threadIdx.x;
  if (i < n) {
    const int v = rs[i] + bsums[i >> 10];
    rs[i] = v;
    cursor[i] = v;
  }
  if (i == n) rs[n] = E;
}

__global__ __launch_bounds__(256) void fill_kernel(
    const int* __restrict__ src, const int* __restrict__ dst,
    int* __restrict__ cursor, int* __restrict__ csr_src, int E) {
  const int stride = gridDim.x * 256;
  for (int e = blockIdx.x * 256 + threadIdx.x; e < E; e += stride) {
    const int pos = atomicAdd(&cursor[dst[e]], 1);
    csr_src[pos] = src[e];
  }
}

// ---------------- Gather (persistent): H[d]=(1+eps)*sp[d]+sum_in sp[src] ----
__global__ __launch_bounds__(256) void gather_kernel(
    const int* __restrict__ rs, const int* __restrict__ csr_src,
    const float2* __restrict__ pairs, const float* __restrict__ eps_p,
    float* __restrict__ H, int nrows) {
  __shared__ float rowbuf[4][128];
  const int lane = threadIdx.x & 63;
  const int wid = threadIdx.x >> 6;
  const float e1 = 1.0f + *eps_p;
  float* row = rowbuf[wid];
  const int sub = lane >> 3;       // which of 8 concurrent edges
  const int p2 = (lane & 7) * 2;   // this lane's 2 nnz pairs

  for (int r = blockIdx.x * 4 + wid; r < nrows; r += gridDim.x * 4) {
    // wave-private row; same-wave DS ops are in-order => no barriers needed
    row[lane] = 0.f;
    row[lane + 64] = 0.f;

    const int beg = rs[r], end = rs[r + 1];
    for (int base = beg; base < end; base += 64) {
      const int cnt = min(64, end - base);
      const int es = (lane < cnt) ? csr_src[base + lane] : 0;
      for (int it = 0; it < cnt; it += 8) {
        const int s = __shfl(es, it + sub);
        if (it + sub < cnt) {
          const float4 pv = *(const float4*)&pairs[(size_t)s * 16 + p2];
          atomicAdd(&row[__float_as_int(pv.y)], pv.x);
          atomicAdd(&row[__float_as_int(pv.w)], pv.z);
        }
      }
    }
    {
      const float2 pv = pairs[(size_t)r * 16 + (lane & 15)];
      if (lane < 16) atomicAdd(&row[__float_as_int(pv.y)], e1 * pv.x);
    }
    H[(size_t)r * 128 + lane] = row[lane];
    H[(size_t)r * 128 + 64 + lane] = row[lane + 64];
  }
}

// ---------------------------------------------------------------------------
extern "C" void kernel_launch(void* const* d_in, const int* in_sizes, int n_in,
                              void* d_out, int out_size, void* d_ws,
                              size_t ws_size, hipStream_t stream) {
  const float* x = (const float*)d_in[0];
  const int* src = (const int*)d_in[1];
  const int* dst = (const int*)d_in[2];
  const float* W_in = (const float*)d_in[3];
  const float* b_in = (const float*)d_in[4];
  const float* W_lin = (const float*)d_in[5];
  const float* b_lin = (const float*)d_in[6];
  const float* eps = (const float*)d_in[7];
  const float* W_out = (const float*)d_in[8];
  const float* b_out = (const float*)d_in[9];
  float* out = (float*)d_out;

  const int n = in_sizes[0] / 128;
  const int E = in_sizes[1];

  char* w = (char*)d_ws;
  float* A = (float*)w;               w += (size_t)n * 128 * 4;
  float* B = (float*)w;               w += (size_t)n * 128 * 4;
  float2* pairs = (float2*)w;         w += (size_t)n * 16 * 8;
  int* deg = (int*)w;                 w += (size_t)n * 4;
  int* rs = (int*)w;                  w += (size_t)(n + 1) * 4;
  int* cursor = (int*)w;              w += (size_t)n * 4;
  int* bsums = (int*)w;               w += 1024 * 4;
  int* csr_src = (int*)w;             w += (size_t)E * 4;
  short* wtAll = (short*)w;           w += (size_t)114688 * 2;

  short* wtIn = wtAll;            // H at +0, L at +16384
  short* wtL0 = wtAll + 32768;
  short* wtL1 = wtAll + 65536;
  short* wtOut = wtAll + 98304;   // H at +0, L at +8192

  const int nb = (n + 1023) / 1024;
  const int gtiles = (n + 63) / 64;
  const dim3 blk(256);

  // ---- CSR build (persistent grids) ----
  hipMemsetAsync(deg, 0, (size_t)n * 4, stream);
  hist_kernel<<<2048, blk, 0, stream>>>(dst, deg, E);
  scan1_kernel<<<nb, blk, 0, stream>>>(deg, rs, bsums, n);
  scan2_kernel<<<1, 64, 0, stream>>>(bsums, nb);
  scan3_kernel<<<(n + 256) / 256, blk, 0, stream>>>(rs, cursor, bsums, n, E);
  fill_kernel<<<2048, blk, 0, stream>>>(src, dst, cursor, csr_src, E);

  // ---- weights -> hi/lo bf16 ----
  wt_build_all_kernel<<<(57344 + 255) / 256, blk, 0, stream>>>(W_in, W_lin,
                                                               W_out, wtAll);

  // ---- h = relu(x @ W_in + b_in) ----
  mfma_gemm_kernel<128, true><<<512, blk, 0, stream>>>(
      x, wtIn, wtIn + 16384, b_in, A, n, gtiles);

  for (int l = 0; l < 2; ++l) {
    short* wt = l ? wtL1 : wtL0;
    // A/B test: layer 0 grid 512, layer 1 grid 1024
    const int ggrid = l ? 1024 : 512;
    mfma_gemm_kernel<128, false><<<ggrid, blk, 0, stream>>>(
        A, wt, wt + 16384, b_lin + (size_t)l * 128, B, n, gtiles);
    maxk_kernel<<<2048, blk, 0, stream>>>(B, pairs, n);
    gather_kernel<<<2048, blk, 0, stream>>>(rs, csr_src, pairs, eps + l, A, n);
  }

  mfma_gemm_kernel<64, false><<<512, blk, 0, stream>>>(
      A, wtOut, wtOut + 8192, b_out, out, n, gtiles);
}

// Round 6
// 837.327 us; speedup vs baseline: 1.1378x; 1.1378x over previous
//
#include <hip/hip_runtime.h>
#include <cstdint>
#include <cstddef>

// ---------------------------------------------------------------------------
// MaxK-GIN. R6: rank-select aggregation (NO LDS atomics — r2/r4/r5 all pinned
// at ~147us = 25.6M LDS atomic RMWs at ~0.3 lane-ops/cy/CU). maxk emits
// (mask u64x2, vals[16] in column order); gather lane owns 2 cols in regs,
// predicated ds_read at rank=popc(mask&below). Intermediates passed to GEMMs
// as bf16 hi/lo planes (no per-tile fp32->bf16 conversion in GEMM).
// ---------------------------------------------------------------------------

typedef __attribute__((ext_vector_type(8))) short bf16x8;
typedef __attribute__((ext_vector_type(4))) float f32x4;

__device__ __forceinline__ unsigned rne_bf16(float v) {
  unsigned u = __float_as_uint(v);
  return (u + 0x7fffu + ((u >> 16) & 1u)) >> 16;
}

// ---------------- fused W^T build: all 4 weights -> hi/lo bf16 --------------
__global__ __launch_bounds__(256) void wt_build_all_kernel(
    const float* __restrict__ W_in, const float* __restrict__ W_lin,
    const float* __restrict__ W_out, short* __restrict__ out) {
  const int i = blockIdx.x * 256 + threadIdx.x;
  if (i >= 57344) return;
  const float* W;
  int nout, local;
  short* H;
  if (i < 16384) {
    W = W_in; nout = 128; local = i; H = out;
  } else if (i < 32768) {
    W = W_lin; nout = 128; local = i - 16384; H = out + 32768;
  } else if (i < 49152) {
    W = W_lin + 16384; nout = 128; local = i - 32768; H = out + 65536;
  } else {
    W = W_out; nout = 64; local = i - 49152; H = out + 98304;
  }
  const int nn = local >> 7, k = local & 127;
  const float v = W[k * nout + nn];
  const unsigned hb = rne_bf16(v);
  const float hf = __uint_as_float(hb << 16);
  const unsigned lb = rne_bf16(v - hf);
  H[local] = (short)hb;
  H[local + nout * 128] = (short)lb;
}

// ---------------- GEMM A (fp32 X): Yh/Yl = split(relu(X@W+b)) ---------------
__global__ __launch_bounds__(256, 2) void gemm_in_kernel(
    const float* __restrict__ X, const short* __restrict__ WtH,
    const short* __restrict__ WtL, const float* __restrict__ bias,
    short* __restrict__ Yh, short* __restrict__ Yl, int nrows, int ntiles) {
  constexpr int NOUT = 128;
  constexpr int NT = NOUT / 16;
  constexpr int LDB = 128 * 2 + 16;
  constexpr int PLANE = NOUT * LDB;
  __shared__ char lds[2 * PLANE];

  const int tid = threadIdx.x;
  for (int u = tid; u < 2 * NOUT * 16; u += 256) {
    const int plane = u / (NOUT * 16);
    const int v = u % (NOUT * 16);
    const int nrow = v >> 4, seg = v & 15;
    const short* src = plane ? WtL : WtH;
    const float4 d = *(const float4*)&src[nrow * 128 + seg * 8];
    *(float4*)&lds[plane * PLANE + nrow * LDB + seg * 16] = d;
  }
  __syncthreads();

  const int lane = tid & 63;
  const int wv = tid >> 6;
  const int li = lane & 15;
  const int kg = lane >> 4;

  float bv[NT];
#pragma unroll
  for (int t = 0; t < NT; ++t) bv[t] = bias[t * 16 + li];

  for (int tile = blockIdx.x; tile < ntiles; tile += gridDim.x) {
    const int row = tile * 64 + wv * 16 + li;
    const int rowc = (row < nrows) ? row : (nrows - 1);
    const float* xrow = X + (size_t)rowc * 128;

    f32x4 acc[NT];
#pragma unroll
    for (int t = 0; t < NT; ++t) acc[t] = (f32x4){0.f, 0.f, 0.f, 0.f};

#pragma unroll
    for (int c = 0; c < 4; ++c) {
      const float4 p0 = *(const float4*)&xrow[c * 32 + kg * 8];
      const float4 p1 = *(const float4*)&xrow[c * 32 + kg * 8 + 4];
      float f[8] = {p0.x, p0.y, p0.z, p0.w, p1.x, p1.y, p1.z, p1.w};
      bf16x8 ah, al;
#pragma unroll
      for (int e = 0; e < 8; ++e) {
        const unsigned hb = rne_bf16(f[e]);
        const float hf = __uint_as_float(hb << 16);
        ah[e] = (short)hb;
        al[e] = (short)rne_bf16(f[e] - hf);
      }
      const int kb = c * 64 + kg * 16;
#pragma unroll
      for (int t = 0; t < NT; ++t) {
        const int boff = (t * 16 + li) * LDB + kb;
        const bf16x8 bh = *(const bf16x8*)&lds[boff];
        const bf16x8 bl = *(const bf16x8*)&lds[PLANE + boff];
        acc[t] = __builtin_amdgcn_mfma_f32_16x16x32_bf16(al, bh, acc[t], 0, 0, 0);
        acc[t] = __builtin_amdgcn_mfma_f32_16x16x32_bf16(ah, bl, acc[t], 0, 0, 0);
        acc[t] = __builtin_amdgcn_mfma_f32_16x16x32_bf16(ah, bh, acc[t], 0, 0, 0);
      }
    }

    const int orow = tile * 64 + wv * 16 + kg * 4;
#pragma unroll
    for (int t = 0; t < NT; ++t) {
      const int col = t * 16 + li;
#pragma unroll
      for (int r = 0; r < 4; ++r) {
        const int rr = orow + r;
        if (rr < nrows) {
          const float o = fmaxf(acc[t][r] + bv[t], 0.f);
          const unsigned hb = rne_bf16(o);
          const float hf = __uint_as_float(hb << 16);
          Yh[(size_t)rr * 128 + col] = (short)hb;
          Yl[(size_t)rr * 128 + col] = (short)rne_bf16(o - hf);
        }
      }
    }
  }
}

// ---------------- GEMM B (bf16-plane X): Y = X@W + b (fp32 out) -------------
template <int NOUT>
__global__ __launch_bounds__(256, 2) void gemm_pl_kernel(
    const short* __restrict__ Xh, const short* __restrict__ Xl,
    const short* __restrict__ WtH, const short* __restrict__ WtL,
    const float* __restrict__ bias, float* __restrict__ Y, int nrows,
    int ntiles) {
  constexpr int NT = NOUT / 16;
  constexpr int LDB = 128 * 2 + 16;
  constexpr int PLANE = NOUT * LDB;
  __shared__ char lds[2 * PLANE];

  const int tid = threadIdx.x;
  for (int u = tid; u < 2 * NOUT * 16; u += 256) {
    const int plane = u / (NOUT * 16);
    const int v = u % (NOUT * 16);
    const int nrow = v >> 4, seg = v & 15;
    const short* src = plane ? WtL : WtH;
    const float4 d = *(const float4*)&src[nrow * 128 + seg * 8];
    *(float4*)&lds[plane * PLANE + nrow * LDB + seg * 16] = d;
  }
  __syncthreads();

  const int lane = tid & 63;
  const int wv = tid >> 6;
  const int li = lane & 15;
  const int kg = lane >> 4;

  float bv[NT];
#pragma unroll
  for (int t = 0; t < NT; ++t) bv[t] = bias[t * 16 + li];

  for (int tile = blockIdx.x; tile < ntiles; tile += gridDim.x) {
    const int row = tile * 64 + wv * 16 + li;
    const int rowc = (row < nrows) ? row : (nrows - 1);
    const short* xh = Xh + (size_t)rowc * 128;
    const short* xl = Xl + (size_t)rowc * 128;

    f32x4 acc[NT];
#pragma unroll
    for (int t = 0; t < NT; ++t) acc[t] = (f32x4){0.f, 0.f, 0.f, 0.f};

#pragma unroll
    for (int c = 0; c < 4; ++c) {
      const bf16x8 ah = *(const bf16x8*)&xh[c * 32 + kg * 8];
      const bf16x8 al = *(const bf16x8*)&xl[c * 32 + kg * 8];
      const int kb = c * 64 + kg * 16;
#pragma unroll
      for (int t = 0; t < NT; ++t) {
        const int boff = (t * 16 + li) * LDB + kb;
        const bf16x8 bh = *(const bf16x8*)&lds[boff];
        const bf16x8 bl = *(const bf16x8*)&lds[PLANE + boff];
        acc[t] = __builtin_amdgcn_mfma_f32_16x16x32_bf16(al, bh, acc[t], 0, 0, 0);
        acc[t] = __builtin_amdgcn_mfma_f32_16x16x32_bf16(ah, bl, acc[t], 0, 0, 0);
        acc[t] = __builtin_amdgcn_mfma_f32_16x16x32_bf16(ah, bh, acc[t], 0, 0, 0);
      }
    }

    const int orow = tile * 64 + wv * 16 + kg * 4;
#pragma unroll
    for (int t = 0; t < NT; ++t) {
      const int col = t * 16 + li;
#pragma unroll
      for (int r = 0; r < 4; ++r) {
        const int rr = orow + r;
        if (rr < nrows) Y[(size_t)rr * NOUT + col] = acc[t][r] + bv[t];
      }
    }
  }
}

// ---------------- MaxK: top-16 -> (mask u64x2, vals[16] col-ordered) --------
__global__ __launch_bounds__(256) void maxk_kernel(
    const float* __restrict__ T, ulonglong2* __restrict__ Ms,
    float* __restrict__ Vs, int nrows) {
  const int lane = threadIdx.x & 63;
  const int wid = threadIdx.x >> 6;
  const unsigned long long below = ((unsigned long long)1 << lane) - 1;

  for (int row = blockIdx.x * 4 + wid; row < nrows; row += gridDim.x * 4) {
    const float o0 = T[(size_t)row * 128 + lane];
    const float o1 = T[(size_t)row * 128 + 64 + lane];
    float v0 = o0, v1 = o1;

#pragma unroll
    for (int it = 0; it < 16; ++it) {
      float m = fmaxf(v0, v1);
#pragma unroll
      for (int off = 32; off; off >>= 1) m = fmaxf(m, __shfl_xor(m, off));
      const unsigned long long b0 = __ballot(v0 == m);
      if (b0) {
        if (lane == __ffsll(b0) - 1) v0 = -INFINITY;
      } else {
        const unsigned long long b1 = __ballot(v1 == m);
        if (lane == __ffsll(b1) - 1) v1 = -INFINITY;
      }
    }
    const unsigned long long m0 = __ballot(v0 == -INFINITY);
    const unsigned long long m1 = __ballot(v1 == -INFINITY);
    if (lane == 0) Ms[row] = make_ulonglong2(m0, m1);
    if ((m0 >> lane) & 1)
      Vs[(size_t)row * 16 + __popcll(m0 & below)] = o0;
    if ((m1 >> lane) & 1)
      Vs[(size_t)row * 16 + __popcll(m0) + __popcll(m1 & below)] = o1;
  }
}

// ---------------- CSR build ------------------------------------------------
__global__ __launch_bounds__(256) void hist_kernel(const int* __restrict__ dst,
                                                   int* __restrict__ deg,
                                                   int E) {
  const int e = blockIdx.x * 256 + threadIdx.x;
  if (e < E) atomicAdd(&deg[dst[e]], 1);
}

__global__ __launch_bounds__(256) void scan1_kernel(
    const int* __restrict__ deg, int* __restrict__ out,
    int* __restrict__ bsums, int n) {
  __shared__ int wsum[4];
  const int t = threadIdx.x;
  const int base = blockIdx.x * 1024 + t * 4;
  int d0 = 0, d1 = 0, d2 = 0, d3 = 0;
  if (base + 0 < n) d0 = deg[base + 0];
  if (base + 1 < n) d1 = deg[base + 1];
  if (base + 2 < n) d2 = deg[base + 2];
  if (base + 3 < n) d3 = deg[base + 3];
  const int s = d0 + d1 + d2 + d3;
  const int lane = t & 63, wid = t >> 6;
  int incl = s;
#pragma unroll
  for (int off = 1; off < 64; off <<= 1) {
    int u = __shfl_up(incl, off);
    if (lane >= off) incl += u;
  }
  if (lane == 63) wsum[wid] = incl;
  __syncthreads();
  int woff = 0;
  for (int w = 0; w < wid; ++w) woff += wsum[w];
  const int excl = woff + incl - s;
  if (base + 0 < n) out[base + 0] = excl;
  if (base + 1 < n) out[base + 1] = excl + d0;
  if (base + 2 < n) out[base + 2] = excl + d0 + d1;
  if (base + 3 < n) out[base + 3] = excl + d0 + d1 + d2;
  if (t == 255) bsums[blockIdx.x] = woff + incl;
}

__global__ __launch_bounds__(64) void scan2_kernel(int* __restrict__ bsums,
                                                   int nb) {
  const int lane = threadIdx.x;
  const int a = (lane < nb) ? bsums[lane] : 0;
  const int b = (lane + 64 < nb) ? bsums[lane + 64] : 0;
  int ia = a, ib = b;
#pragma unroll
  for (int off = 1; off < 64; off <<= 1) {
    const int ta = __shfl_up(ia, off);
    const int tb = __shfl_up(ib, off);
    if (lane >= off) { ia += ta; ib += tb; }
  }
  const int totA = __shfl(ia, 63);
  if (lane < nb) bsums[lane] = ia - a;
  if (lane + 64 < nb) bsums[lane + 64] = totA + ib - b;
}

__global__ __launch_bounds__(256) void scan3_kernel(
    int* __restrict__ rs, int* __restrict__ cursor,
    const int* __restrict__ bsums, int n, int E) {
  const int i = blockIdx.x * 256 + threadIdx.x;
  if (i < n) {
    const int v = rs[i] + bsums[i >> 10];
    rs[i] = v;
    cursor[i] = v;
  }
  if (i == n) rs[n] = E;
}

__global__ __launch_bounds__(256) void fill_kernel(
    const int* __restrict__ src, const int* __restrict__ dst,
    int* __restrict__ cursor, int* __restrict__ csr_src, int E) {
  const int e = blockIdx.x * 256 + threadIdx.x;
  if (e < E) {
    const int pos = atomicAdd(&cursor[dst[e]], 1);
    csr_src[pos] = src[e];
  }
}

// ---------------- Gather v2 (rank-select, no atomics) -----------------------
// wave per dst row; lane owns cols {lane, lane+64} in registers.
// emits bf16 hi/lo planes for the next GEMM.
__global__ __launch_bounds__(256) void gather2_kernel(
    const int* __restrict__ rs, const int* __restrict__ csr_src,
    const ulonglong2* __restrict__ Ms, const float* __restrict__ Vs,
    const float* __restrict__ eps_p, short* __restrict__ Ah,
    short* __restrict__ Al, int nrows) {
  __shared__ __align__(16) float sv[4][16][16];
  __shared__ ulonglong2 sm[4][16];
  const int lane = threadIdx.x & 63;
  const int wid = threadIdx.x >> 6;
  const float e1 = 1.0f + *eps_p;
  const unsigned long long below = ((unsigned long long)1 << lane) - 1;
  const int ee = lane >> 2;      // staged edge slot (0..15)
  const int q = lane & 3;        // quarter of the 16 vals

  for (int r = blockIdx.x * 4 + wid; r < nrows; r += gridDim.x * 4) {
    float acc0 = 0.f, acc1 = 0.f;
    const int beg = rs[r], end = rs[r + 1];

    for (int base = beg; base < end; base += 16) {
      const int cnt = min(16, end - base);
      if (ee < cnt) {
        const int s = csr_src[base + ee];
        if (q == 0) sm[wid][ee] = Ms[s];
        const float4 v = *(const float4*)&Vs[(size_t)s * 16 + q * 4];
        *(float4*)&sv[wid][ee][q * 4] = v;
      }
      // same-wave DS ops are in-order; compiler inserts lgkm waits.
      for (int e = 0; e < cnt; ++e) {
        const ulonglong2 mm = sm[wid][e];
        if ((mm.x >> lane) & 1)
          acc0 += sv[wid][e][__popcll(mm.x & below)];
        if ((mm.y >> lane) & 1)
          acc1 += sv[wid][e][__popcll(mm.x) + __popcll(mm.y & below)];
      }
    }

    // self term: (1+eps) * h_sparse[r]
    {
      const ulonglong2 mr = Ms[r];
      if ((mr.x >> lane) & 1)
        acc0 += e1 * Vs[(size_t)r * 16 + __popcll(mr.x & below)];
      if ((mr.y >> lane) & 1)
        acc1 += e1 * Vs[(size_t)r * 16 + __popcll(mr.x) + __popcll(mr.y & below)];
    }

    // emit bf16 hi/lo planes
    const unsigned h0 = rne_bf16(acc0);
    const unsigned h1 = rne_bf16(acc1);
    Ah[(size_t)r * 128 + lane] = (short)h0;
    Ah[(size_t)r * 128 + 64 + lane] = (short)h1;
    Al[(size_t)r * 128 + lane] =
        (short)rne_bf16(acc0 - __uint_as_float(h0 << 16));
    Al[(size_t)r * 128 + 64 + lane] =
        (short)rne_bf16(acc1 - __uint_as_float(h1 << 16));
  }
}

// ---------------------------------------------------------------------------
extern "C" void kernel_launch(void* const* d_in, const int* in_sizes, int n_in,
                              void* d_out, int out_size, void* d_ws,
                              size_t ws_size, hipStream_t stream) {
  const float* x = (const float*)d_in[0];
  const int* src = (const int*)d_in[1];
  const int* dst = (const int*)d_in[2];
  const float* W_in = (const float*)d_in[3];
  const float* b_in = (const float*)d_in[4];
  const float* W_lin = (const float*)d_in[5];
  const float* b_lin = (const float*)d_in[6];
  const float* eps = (const float*)d_in[7];
  const float* W_out = (const float*)d_in[8];
  const float* b_out = (const float*)d_in[9];
  float* out = (float*)d_out;

  const int n = in_sizes[0] / 128;
  const int E = in_sizes[1];

  char* w = (char*)d_ws;
  float* B = (float*)w;               w += (size_t)n * 128 * 4;   // fp32 gemm out
  ulonglong2* Ms = (ulonglong2*)w;    w += (size_t)n * 16;        // masks
  float* Vs = (float*)w;              w += (size_t)n * 16 * 4;    // col-ordered vals
  int* deg = (int*)w;                 w += (size_t)n * 4;
  int* rs = (int*)w;                  w += (size_t)(n + 1) * 4;
  int* cursor = (int*)w;              w += (size_t)n * 4;
  int* bsums = (int*)w;               w += 1024 * 4;
  int* csr_src = (int*)w;             w += (size_t)E * 4;
  short* wtAll = (short*)w;           w += (size_t)114688 * 2;
  short* Ah = (short*)w;              w += (size_t)n * 128 * 2;   // hi plane
  short* Al = (short*)w;              w += (size_t)n * 128 * 2;   // lo plane

  short* wtIn = wtAll;
  short* wtL0 = wtAll + 32768;
  short* wtL1 = wtAll + 65536;
  short* wtOut = wtAll + 98304;

  const int nb = (n + 1023) / 1024;
  const int gtiles = (n + 63) / 64;
  const dim3 blk(256);

  // ---- CSR build ----
  hipMemsetAsync(deg, 0, (size_t)n * 4, stream);
  hist_kernel<<<(E + 255) / 256, blk, 0, stream>>>(dst, deg, E);
  scan1_kernel<<<nb, blk, 0, stream>>>(deg, rs, bsums, n);
  scan2_kernel<<<1, 64, 0, stream>>>(bsums, nb);
  scan3_kernel<<<(n + 256) / 256, blk, 0, stream>>>(rs, cursor, bsums, n, E);
  fill_kernel<<<(E + 255) / 256, blk, 0, stream>>>(src, dst, cursor, csr_src, E);

  // ---- weights -> hi/lo bf16 ----
  wt_build_all_kernel<<<(57344 + 255) / 256, blk, 0, stream>>>(W_in, W_lin,
                                                               W_out, wtAll);

  // ---- h = relu(x @ W_in + b_in) -> planes ----
  gemm_in_kernel<<<512, blk, 0, stream>>>(x, wtIn, wtIn + 16384, b_in, Ah, Al,
                                          n, gtiles);

  for (int l = 0; l < 2; ++l) {
    short* wt = l ? wtL1 : wtL0;
    gemm_pl_kernel<128><<<512, blk, 0, stream>>>(
        Ah, Al, wt, wt + 16384, b_lin + (size_t)l * 128, B, n, gtiles);
    maxk_kernel<<<2048, blk, 0, stream>>>(B, Ms, Vs, n);
    gather2_kernel<<<2048, blk, 0, stream>>>(rs, csr_src, Ms, Vs, eps + l, Ah,
                                             Al, n);
  }

  gemm_pl_kernel<64><<<512, blk, 0, stream>>>(Ah, Al, wtOut, wtOut + 8192,
                                              b_out, out, n, gtiles);
}

// Round 7
// 703.800 us; speedup vs baseline: 1.3536x; 1.1897x over previous
//
#include <hip/hip_runtime.h>
#include <cstdint>
#include <cstddef>

// ---------------------------------------------------------------------------
// MaxK-GIN. R7: maxk via radix-select (32 ballot rounds, no shuffle chains —
// r6's iterative-max spent ~25k cyc/row in dependent ds_swizzle latency).
// Aggregation stays rank-select (no LDS atomics). GEMMs split-bf16 MFMA.
// ---------------------------------------------------------------------------

typedef __attribute__((ext_vector_type(8))) short bf16x8;
typedef __attribute__((ext_vector_type(4))) float f32x4;

__device__ __forceinline__ unsigned rne_bf16(float v) {
  unsigned u = __float_as_uint(v);
  return (u + 0x7fffu + ((u >> 16) & 1u)) >> 16;
}

// ---------------- fused W^T build: all 4 weights -> hi/lo bf16 --------------
__global__ __launch_bounds__(256) void wt_build_all_kernel(
    const float* __restrict__ W_in, const float* __restrict__ W_lin,
    const float* __restrict__ W_out, short* __restrict__ out) {
  const int i = blockIdx.x * 256 + threadIdx.x;
  if (i >= 57344) return;
  const float* W;
  int nout, local;
  short* H;
  if (i < 16384) {
    W = W_in; nout = 128; local = i; H = out;
  } else if (i < 32768) {
    W = W_lin; nout = 128; local = i - 16384; H = out + 32768;
  } else if (i < 49152) {
    W = W_lin + 16384; nout = 128; local = i - 32768; H = out + 65536;
  } else {
    W = W_out; nout = 64; local = i - 49152; H = out + 98304;
  }
  const int nn = local >> 7, k = local & 127;
  const float v = W[k * nout + nn];
  const unsigned hb = rne_bf16(v);
  const float hf = __uint_as_float(hb << 16);
  const unsigned lb = rne_bf16(v - hf);
  H[local] = (short)hb;
  H[local + nout * 128] = (short)lb;
}

// ---------------- GEMM A (fp32 X): Yh/Yl = split(relu(X@W+b)) ---------------
__global__ __launch_bounds__(256, 2) void gemm_in_kernel(
    const float* __restrict__ X, const short* __restrict__ WtH,
    const short* __restrict__ WtL, const float* __restrict__ bias,
    short* __restrict__ Yh, short* __restrict__ Yl, int nrows, int ntiles) {
  constexpr int NOUT = 128;
  constexpr int NT = NOUT / 16;
  constexpr int LDB = 128 * 2 + 16;
  constexpr int PLANE = NOUT * LDB;
  __shared__ char lds[2 * PLANE];

  const int tid = threadIdx.x;
  for (int u = tid; u < 2 * NOUT * 16; u += 256) {
    const int plane = u / (NOUT * 16);
    const int v = u % (NOUT * 16);
    const int nrow = v >> 4, seg = v & 15;
    const short* src = plane ? WtL : WtH;
    const float4 d = *(const float4*)&src[nrow * 128 + seg * 8];
    *(float4*)&lds[plane * PLANE + nrow * LDB + seg * 16] = d;
  }
  __syncthreads();

  const int lane = tid & 63;
  const int wv = tid >> 6;
  const int li = lane & 15;
  const int kg = lane >> 4;

  float bv[NT];
#pragma unroll
  for (int t = 0; t < NT; ++t) bv[t] = bias[t * 16 + li];

  for (int tile = blockIdx.x; tile < ntiles; tile += gridDim.x) {
    const int row = tile * 64 + wv * 16 + li;
    const int rowc = (row < nrows) ? row : (nrows - 1);
    const float* xrow = X + (size_t)rowc * 128;

    f32x4 acc[NT];
#pragma unroll
    for (int t = 0; t < NT; ++t) acc[t] = (f32x4){0.f, 0.f, 0.f, 0.f};

#pragma unroll
    for (int c = 0; c < 4; ++c) {
      const float4 p0 = *(const float4*)&xrow[c * 32 + kg * 8];
      const float4 p1 = *(const float4*)&xrow[c * 32 + kg * 8 + 4];
      float f[8] = {p0.x, p0.y, p0.z, p0.w, p1.x, p1.y, p1.z, p1.w};
      bf16x8 ah, al;
#pragma unroll
      for (int e = 0; e < 8; ++e) {
        const unsigned hb = rne_bf16(f[e]);
        const float hf = __uint_as_float(hb << 16);
        ah[e] = (short)hb;
        al[e] = (short)rne_bf16(f[e] - hf);
      }
      const int kb = c * 64 + kg * 16;
#pragma unroll
      for (int t = 0; t < NT; ++t) {
        const int boff = (t * 16 + li) * LDB + kb;
        const bf16x8 bh = *(const bf16x8*)&lds[boff];
        const bf16x8 bl = *(const bf16x8*)&lds[PLANE + boff];
        acc[t] = __builtin_amdgcn_mfma_f32_16x16x32_bf16(al, bh, acc[t], 0, 0, 0);
        acc[t] = __builtin_amdgcn_mfma_f32_16x16x32_bf16(ah, bl, acc[t], 0, 0, 0);
        acc[t] = __builtin_amdgcn_mfma_f32_16x16x32_bf16(ah, bh, acc[t], 0, 0, 0);
      }
    }

    const int orow = tile * 64 + wv * 16 + kg * 4;
#pragma unroll
    for (int t = 0; t < NT; ++t) {
      const int col = t * 16 + li;
#pragma unroll
      for (int r = 0; r < 4; ++r) {
        const int rr = orow + r;
        if (rr < nrows) {
          const float o = fmaxf(acc[t][r] + bv[t], 0.f);
          const unsigned hb = rne_bf16(o);
          const float hf = __uint_as_float(hb << 16);
          Yh[(size_t)rr * 128 + col] = (short)hb;
          Yl[(size_t)rr * 128 + col] = (short)rne_bf16(o - hf);
        }
      }
    }
  }
}

// ---------------- GEMM B (bf16-plane X): Y = X@W + b (fp32 out) -------------
template <int NOUT>
__global__ __launch_bounds__(256, 2) void gemm_pl_kernel(
    const short* __restrict__ Xh, const short* __restrict__ Xl,
    const short* __restrict__ WtH, const short* __restrict__ WtL,
    const float* __restrict__ bias, float* __restrict__ Y, int nrows,
    int ntiles) {
  constexpr int NT = NOUT / 16;
  constexpr int LDB = 128 * 2 + 16;
  constexpr int PLANE = NOUT * LDB;
  __shared__ char lds[2 * PLANE];

  const int tid = threadIdx.x;
  for (int u = tid; u < 2 * NOUT * 16; u += 256) {
    const int plane = u / (NOUT * 16);
    const int v = u % (NOUT * 16);
    const int nrow = v >> 4, seg = v & 15;
    const short* src = plane ? WtL : WtH;
    const float4 d = *(const float4*)&src[nrow * 128 + seg * 8];
    *(float4*)&lds[plane * PLANE + nrow * LDB + seg * 16] = d;
  }
  __syncthreads();

  const int lane = tid & 63;
  const int wv = tid >> 6;
  const int li = lane & 15;
  const int kg = lane >> 4;

  float bv[NT];
#pragma unroll
  for (int t = 0; t < NT; ++t) bv[t] = bias[t * 16 + li];

  for (int tile = blockIdx.x; tile < ntiles; tile += gridDim.x) {
    const int row = tile * 64 + wv * 16 + li;
    const int rowc = (row < nrows) ? row : (nrows - 1);
    const short* xh = Xh + (size_t)rowc * 128;
    const short* xl = Xl + (size_t)rowc * 128;

    f32x4 acc[NT];
#pragma unroll
    for (int t = 0; t < NT; ++t) acc[t] = (f32x4){0.f, 0.f, 0.f, 0.f};

#pragma unroll
    for (int c = 0; c < 4; ++c) {
      const bf16x8 ah = *(const bf16x8*)&xh[c * 32 + kg * 8];
      const bf16x8 al = *(const bf16x8*)&xl[c * 32 + kg * 8];
      const int kb = c * 64 + kg * 16;
#pragma unroll
      for (int t = 0; t < NT; ++t) {
        const int boff = (t * 16 + li) * LDB + kb;
        const bf16x8 bh = *(const bf16x8*)&lds[boff];
        const bf16x8 bl = *(const bf16x8*)&lds[PLANE + boff];
        acc[t] = __builtin_amdgcn_mfma_f32_16x16x32_bf16(al, bh, acc[t], 0, 0, 0);
        acc[t] = __builtin_amdgcn_mfma_f32_16x16x32_bf16(ah, bl, acc[t], 0, 0, 0);
        acc[t] = __builtin_amdgcn_mfma_f32_16x16x32_bf16(ah, bh, acc[t], 0, 0, 0);
      }
    }

    const int orow = tile * 64 + wv * 16 + kg * 4;
#pragma unroll
    for (int t = 0; t < NT; ++t) {
      const int col = t * 16 + li;
#pragma unroll
      for (int r = 0; r < 4; ++r) {
        const int rr = orow + r;
        if (rr < nrows) Y[(size_t)rr * NOUT + col] = acc[t][r] + bv[t];
      }
    }
  }
}

// ---------------- MaxK v2: radix-select top-16 -> (mask, col-ordered vals) --
// Monotone key per float; 32 ballot rounds find the 16th-largest key P.
// No cross-lane data movement (ballots are v_cmp + scalar popc only).
__global__ __launch_bounds__(256) void maxk_kernel(
    const float* __restrict__ T, ulonglong2* __restrict__ Ms,
    float* __restrict__ Vs, int nrows) {
  const int lane = threadIdx.x & 63;
  const int wid = threadIdx.x >> 6;
  const unsigned long long below = ((unsigned long long)1 << lane) - 1;

  for (int row = blockIdx.x * 4 + wid; row < nrows; row += gridDim.x * 4) {
    const float o0 = T[(size_t)row * 128 + lane];
    const float o1 = T[(size_t)row * 128 + 64 + lane];
    const unsigned u0 = __float_as_uint(o0);
    const unsigned u1 = __float_as_uint(o1);
    const unsigned k0 = u0 ^ (((unsigned)((int)u0 >> 31)) | 0x80000000u);
    const unsigned k1 = u1 ^ (((unsigned)((int)u1 >> 31)) | 0x80000000u);

    unsigned P = 0;
    int kth = 16;
#pragma unroll
    for (int b = 31; b >= 0; --b) {
      const unsigned long long ball0 = __ballot(((k0 ^ P) >> b) == 1u);
      const unsigned long long ball1 = __ballot(((k1 ^ P) >> b) == 1u);
      const int c = __popcll(ball0) + __popcll(ball1);
      if (c >= kth)
        P |= (1u << b);
      else
        kth -= c;
    }
    // P == 16th-largest key. Select keys > P, then lowest-index keys == P.
    const bool gt0 = k0 > P, gt1 = k1 > P;
    const unsigned long long g0 = __ballot(gt0);
    const unsigned long long g1 = __ballot(gt1);
    const int need = 16 - __popcll(g0) - __popcll(g1);
    const unsigned long long e0 = __ballot(k0 == P);
    const unsigned long long e1 = __ballot(k1 == P);
    const int need1 = need - __popcll(e0);
    const bool s0 = ((e0 >> lane) & 1) && ((int)__popcll(e0 & below) < need);
    const bool s1 = ((e1 >> lane) & 1) && ((int)__popcll(e1 & below) < need1);
    const unsigned long long m0 = __ballot(gt0 || s0);
    const unsigned long long m1 = __ballot(gt1 || s1);

    if (lane == 0) Ms[row] = make_ulonglong2(m0, m1);
    if ((m0 >> lane) & 1)
      Vs[(size_t)row * 16 + __popcll(m0 & below)] = o0;
    if ((m1 >> lane) & 1)
      Vs[(size_t)row * 16 + __popcll(m0) + __popcll(m1 & below)] = o1;
  }
}

// ---------------- CSR build ------------------------------------------------
__global__ __launch_bounds__(256) void hist_kernel(const int* __restrict__ dst,
                                                   int* __restrict__ deg,
                                                   int E) {
  const int e = blockIdx.x * 256 + threadIdx.x;
  if (e < E) atomicAdd(&deg[dst[e]], 1);
}

__global__ __launch_bounds__(256) void scan1_kernel(
    const int* __restrict__ deg, int* __restrict__ out,
    int* __restrict__ bsums, int n) {
  __shared__ int wsum[4];
  const int t = threadIdx.x;
  const int base = blockIdx.x * 1024 + t * 4;
  int d0 = 0, d1 = 0, d2 = 0, d3 = 0;
  if (base + 0 < n) d0 = deg[base + 0];
  if (base + 1 < n) d1 = deg[base + 1];
  if (base + 2 < n) d2 = deg[base + 2];
  if (base + 3 < n) d3 = deg[base + 3];
  const int s = d0 + d1 + d2 + d3;
  const int lane = t & 63, wid = t >> 6;
  int incl = s;
#pragma unroll
  for (int off = 1; off < 64; off <<= 1) {
    int u = __shfl_up(incl, off);
    if (lane >= off) incl += u;
  }
  if (lane == 63) wsum[wid] = incl;
  __syncthreads();
  int woff = 0;
  for (int w = 0; w < wid; ++w) woff += wsum[w];
  const int excl = woff + incl - s;
  if (base + 0 < n) out[base + 0] = excl;
  if (base + 1 < n) out[base + 1] = excl + d0;
  if (base + 2 < n) out[base + 2] = excl + d0 + d1;
  if (base + 3 < n) out[base + 3] = excl + d0 + d1 + d2;
  if (t == 255) bsums[blockIdx.x] = woff + incl;
}

__global__ __launch_bounds__(64) void scan2_kernel(int* __restrict__ bsums,
                                                   int nb) {
  const int lane = threadIdx.x;
  const int a = (lane < nb) ? bsums[lane] : 0;
  const int b = (lane + 64 < nb) ? bsums[lane + 64] : 0;
  int ia = a, ib = b;
#pragma unroll
  for (int off = 1; off < 64; off <<= 1) {
    const int ta = __shfl_up(ia, off);
    const int tb = __shfl_up(ib, off);
    if (lane >= off) { ia += ta; ib += tb; }
  }
  const int totA = __shfl(ia, 63);
  if (lane < nb) bsums[lane] = ia - a;
  if (lane + 64 < nb) bsums[lane + 64] = totA + ib - b;
}

__global__ __launch_bounds__(256) void scan3_kernel(
    int* __restrict__ rs, int* __restrict__ cursor,
    const int* __restrict__ bsums, int n, int E) {
  const int i = blockIdx.x * 256 + threadIdx.x;
  if (i < n) {
    const int v = rs[i] + bsums[i >> 10];
    rs[i] = v;
    cursor[i] = v;
  }
  if (i == n) rs[n] = E;
}

__global__ __launch_bounds__(256) void fill_kernel(
    const int* __restrict__ src, const int* __restrict__ dst,
    int* __restrict__ cursor, int* __restrict__ csr_src, int E) {
  const int e = blockIdx.x * 256 + threadIdx.x;
  if (e < E) {
    const int pos = atomicAdd(&cursor[dst[e]], 1);
    csr_src[pos] = src[e];
  }
}

// ---------------- Gather v2 (rank-select, no atomics) -----------------------
__global__ __launch_bounds__(256) void gather2_kernel(
    const int* __restrict__ rs, const int* __restrict__ csr_src,
    const ulonglong2* __restrict__ Ms, const float* __restrict__ Vs,
    const float* __restrict__ eps_p, short* __restrict__ Ah,
    short* __restrict__ Al, int nrows) {
  __shared__ __align__(16) float sv[4][16][16];
  __shared__ ulonglong2 sm[4][16];
  const int lane = threadIdx.x & 63;
  const int wid = threadIdx.x >> 6;
  const float e1 = 1.0f + *eps_p;
  const unsigned long long below = ((unsigned long long)1 << lane) - 1;
  const int ee = lane >> 2;
  const int q = lane & 3;

  for (int r = blockIdx.x * 4 + wid; r < nrows; r += gridDim.x * 4) {
    float acc0 = 0.f, acc1 = 0.f;
    const int beg = rs[r], end = rs[r + 1];

    for (int base = beg; base < end; base += 16) {
      const int cnt = min(16, end - base);
      if (ee < cnt) {
        const int s = csr_src[base + ee];
        if (q == 0) sm[wid][ee] = Ms[s];
        const float4 v = *(const float4*)&Vs[(size_t)s * 16 + q * 4];
        *(float4*)&sv[wid][ee][q * 4] = v;
      }
      for (int e = 0; e < cnt; ++e) {
        const ulonglong2 mm = sm[wid][e];
        if ((mm.x >> lane) & 1)
          acc0 += sv[wid][e][__popcll(mm.x & below)];
        if ((mm.y >> lane) & 1)
          acc1 += sv[wid][e][__popcll(mm.x) + __popcll(mm.y & below)];
      }
    }

    {
      const ulonglong2 mr = Ms[r];
      if ((mr.x >> lane) & 1)
        acc0 += e1 * Vs[(size_t)r * 16 + __popcll(mr.x & below)];
      if ((mr.y >> lane) & 1)
        acc1 += e1 * Vs[(size_t)r * 16 + __popcll(mr.x) + __popcll(mr.y & below)];
    }

    const unsigned h0 = rne_bf16(acc0);
    const unsigned h1 = rne_bf16(acc1);
    Ah[(size_t)r * 128 + lane] = (short)h0;
    Ah[(size_t)r * 128 + 64 + lane] = (short)h1;
    Al[(size_t)r * 128 + lane] =
        (short)rne_bf16(acc0 - __uint_as_float(h0 << 16));
    Al[(size_t)r * 128 + 64 + lane] =
        (short)rne_bf16(acc1 - __uint_as_float(h1 << 16));
  }
}

// ---------------------------------------------------------------------------
extern "C" void kernel_launch(void* const* d_in, const int* in_sizes, int n_in,
                              void* d_out, int out_size, void* d_ws,
                              size_t ws_size, hipStream_t stream) {
  const float* x = (const float*)d_in[0];
  const int* src = (const int*)d_in[1];
  const int* dst = (const int*)d_in[2];
  const float* W_in = (const float*)d_in[3];
  const float* b_in = (const float*)d_in[4];
  const float* W_lin = (const float*)d_in[5];
  const float* b_lin = (const float*)d_in[6];
  const float* eps = (const float*)d_in[7];
  const float* W_out = (const float*)d_in[8];
  const float* b_out = (const float*)d_in[9];
  float* out = (float*)d_out;

  const int n = in_sizes[0] / 128;
  const int E = in_sizes[1];

  char* w = (char*)d_ws;
  float* B = (float*)w;               w += (size_t)n * 128 * 4;
  ulonglong2* Ms = (ulonglong2*)w;    w += (size_t)n * 16;
  float* Vs = (float*)w;              w += (size_t)n * 16 * 4;
  int* deg = (int*)w;                 w += (size_t)n * 4;
  int* rs = (int*)w;                  w += (size_t)(n + 1) * 4;
  int* cursor = (int*)w;              w += (size_t)n * 4;
  int* bsums = (int*)w;               w += 1024 * 4;
  int* csr_src = (int*)w;             w += (size_t)E * 4;
  short* wtAll = (short*)w;           w += (size_t)114688 * 2;
  short* Ah = (short*)w;              w += (size_t)n * 128 * 2;
  short* Al = (short*)w;              w += (size_t)n * 128 * 2;

  short* wtIn = wtAll;
  short* wtL0 = wtAll + 32768;
  short* wtL1 = wtAll + 65536;
  short* wtOut = wtAll + 98304;

  const int nb = (n + 1023) / 1024;
  const int gtiles = (n + 63) / 64;
  const dim3 blk(256);

  // ---- CSR build ----
  hipMemsetAsync(deg, 0, (size_t)n * 4, stream);
  hist_kernel<<<(E + 255) / 256, blk, 0, stream>>>(dst, deg, E);
  scan1_kernel<<<nb, blk, 0, stream>>>(deg, rs, bsums, n);
  scan2_kernel<<<1, 64, 0, stream>>>(bsums, nb);
  scan3_kernel<<<(n + 256) / 256, blk, 0, stream>>>(rs, cursor, bsums, n, E);
  fill_kernel<<<(E + 255) / 256, blk, 0, stream>>>(src, dst, cursor, csr_src, E);

  // ---- weights -> hi/lo bf16 ----
  wt_build_all_kernel<<<(57344 + 255) / 256, blk, 0, stream>>>(W_in, W_lin,
                                                               W_out, wtAll);

  // ---- h = relu(x @ W_in + b_in) -> planes ----
  gemm_in_kernel<<<512, blk, 0, stream>>>(x, wtIn, wtIn + 16384, b_in, Ah, Al,
                                          n, gtiles);

  for (int l = 0; l < 2; ++l) {
    short* wt = l ? wtL1 : wtL0;
    gemm_pl_kernel<128><<<512, blk, 0, stream>>>(
        Ah, Al, wt, wt + 16384, b_lin + (size_t)l * 128, B, n, gtiles);
    maxk_kernel<<<2048, blk, 0, stream>>>(B, Ms, Vs, n);
    gather2_kernel<<<2048, blk, 0, stream>>>(rs, csr_src, Ms, Vs, eps + l, Ah,
                                             Al, n);
  }

  gemm_pl_kernel<64><<<512, blk, 0, stream>>>(Ah, Al, wtOut, wtOut + 8192,
                                              b_out, out, n, gtiles);
}

// Round 8
// 582.075 us; speedup vs baseline: 1.6367x; 1.2091x over previous
//
#include <hip/hip_runtime.h>
#include <cstdint>
#include <cstddef>

// ---------------------------------------------------------------------------
// MaxK-GIN. R8: CSR build rebuilt as atomic-light two-level binning
// (bhist/bscan/bin/bbuild) — r7's hist+fill spent ~190us in 3.2M global
// atomics + 64B-amplified scattered 4B writes. maxk stays radix-select,
// aggregation stays rank-select, GEMMs split-bf16 MFMA.
// ---------------------------------------------------------------------------

typedef __attribute__((ext_vector_type(8))) short bf16x8;
typedef __attribute__((ext_vector_type(4))) float f32x4;

#define BSHIFT 8
#define NBUK 512  // covers dst>>8 for n <= 131072

__device__ __forceinline__ unsigned rne_bf16(float v) {
  unsigned u = __float_as_uint(v);
  return (u + 0x7fffu + ((u >> 16) & 1u)) >> 16;
}

// ---------------- fused W^T build: all 4 weights -> hi/lo bf16 --------------
__global__ __launch_bounds__(256) void wt_build_all_kernel(
    const float* __restrict__ W_in, const float* __restrict__ W_lin,
    const float* __restrict__ W_out, short* __restrict__ out) {
  const int i = blockIdx.x * 256 + threadIdx.x;
  if (i >= 57344) return;
  const float* W;
  int nout, local;
  short* H;
  if (i < 16384) {
    W = W_in; nout = 128; local = i; H = out;
  } else if (i < 32768) {
    W = W_lin; nout = 128; local = i - 16384; H = out + 32768;
  } else if (i < 49152) {
    W = W_lin + 16384; nout = 128; local = i - 32768; H = out + 65536;
  } else {
    W = W_out; nout = 64; local = i - 49152; H = out + 98304;
  }
  const int nn = local >> 7, k = local & 127;
  const float v = W[k * nout + nn];
  const unsigned hb = rne_bf16(v);
  const float hf = __uint_as_float(hb << 16);
  const unsigned lb = rne_bf16(v - hf);
  H[local] = (short)hb;
  H[local + nout * 128] = (short)lb;
}

// ---------------- GEMM A (fp32 X): Yh/Yl = split(relu(X@W+b)) ---------------
__global__ __launch_bounds__(256, 2) void gemm_in_kernel(
    const float* __restrict__ X, const short* __restrict__ WtH,
    const short* __restrict__ WtL, const float* __restrict__ bias,
    short* __restrict__ Yh, short* __restrict__ Yl, int nrows, int ntiles) {
  constexpr int NOUT = 128;
  constexpr int NT = NOUT / 16;
  constexpr int LDB = 128 * 2 + 16;
  constexpr int PLANE = NOUT * LDB;
  __shared__ char lds[2 * PLANE];

  const int tid = threadIdx.x;
  for (int u = tid; u < 2 * NOUT * 16; u += 256) {
    const int plane = u / (NOUT * 16);
    const int v = u % (NOUT * 16);
    const int nrow = v >> 4, seg = v & 15;
    const short* src = plane ? WtL : WtH;
    const float4 d = *(const float4*)&src[nrow * 128 + seg * 8];
    *(float4*)&lds[plane * PLANE + nrow * LDB + seg * 16] = d;
  }
  __syncthreads();

  const int lane = tid & 63;
  const int wv = tid >> 6;
  const int li = lane & 15;
  const int kg = lane >> 4;

  float bv[NT];
#pragma unroll
  for (int t = 0; t < NT; ++t) bv[t] = bias[t * 16 + li];

  for (int tile = blockIdx.x; tile < ntiles; tile += gridDim.x) {
    const int row = tile * 64 + wv * 16 + li;
    const int rowc = (row < nrows) ? row : (nrows - 1);
    const float* xrow = X + (size_t)rowc * 128;

    f32x4 acc[NT];
#pragma unroll
    for (int t = 0; t < NT; ++t) acc[t] = (f32x4){0.f, 0.f, 0.f, 0.f};

#pragma unroll
    for (int c = 0; c < 4; ++c) {
      const float4 p0 = *(const float4*)&xrow[c * 32 + kg * 8];
      const float4 p1 = *(const float4*)&xrow[c * 32 + kg * 8 + 4];
      float f[8] = {p0.x, p0.y, p0.z, p0.w, p1.x, p1.y, p1.z, p1.w};
      bf16x8 ah, al;
#pragma unroll
      for (int e = 0; e < 8; ++e) {
        const unsigned hb = rne_bf16(f[e]);
        const float hf = __uint_as_float(hb << 16);
        ah[e] = (short)hb;
        al[e] = (short)rne_bf16(f[e] - hf);
      }
      const int kb = c * 64 + kg * 16;
#pragma unroll
      for (int t = 0; t < NT; ++t) {
        const int boff = (t * 16 + li) * LDB + kb;
        const bf16x8 bh = *(const bf16x8*)&lds[boff];
        const bf16x8 bl = *(const bf16x8*)&lds[PLANE + boff];
        acc[t] = __builtin_amdgcn_mfma_f32_16x16x32_bf16(al, bh, acc[t], 0, 0, 0);
        acc[t] = __builtin_amdgcn_mfma_f32_16x16x32_bf16(ah, bl, acc[t], 0, 0, 0);
        acc[t] = __builtin_amdgcn_mfma_f32_16x16x32_bf16(ah, bh, acc[t], 0, 0, 0);
      }
    }

    const int orow = tile * 64 + wv * 16 + kg * 4;
#pragma unroll
    for (int t = 0; t < NT; ++t) {
      const int col = t * 16 + li;
#pragma unroll
      for (int r = 0; r < 4; ++r) {
        const int rr = orow + r;
        if (rr < nrows) {
          const float o = fmaxf(acc[t][r] + bv[t], 0.f);
          const unsigned hb = rne_bf16(o);
          const float hf = __uint_as_float(hb << 16);
          Yh[(size_t)rr * 128 + col] = (short)hb;
          Yl[(size_t)rr * 128 + col] = (short)rne_bf16(o - hf);
        }
      }
    }
  }
}

// ---------------- GEMM B (bf16-plane X): Y = X@W + b (fp32 out) -------------
template <int NOUT>
__global__ __launch_bounds__(256, 2) void gemm_pl_kernel(
    const short* __restrict__ Xh, const short* __restrict__ Xl,
    const short* __restrict__ WtH, const short* __restrict__ WtL,
    const float* __restrict__ bias, float* __restrict__ Y, int nrows,
    int ntiles) {
  constexpr int NT = NOUT / 16;
  constexpr int LDB = 128 * 2 + 16;
  constexpr int PLANE = NOUT * LDB;
  __shared__ char lds[2 * PLANE];

  const int tid = threadIdx.x;
  for (int u = tid; u < 2 * NOUT * 16; u += 256) {
    const int plane = u / (NOUT * 16);
    const int v = u % (NOUT * 16);
    const int nrow = v >> 4, seg = v & 15;
    const short* src = plane ? WtL : WtH;
    const float4 d = *(const float4*)&src[nrow * 128 + seg * 8];
    *(float4*)&lds[plane * PLANE + nrow * LDB + seg * 16] = d;
  }
  __syncthreads();

  const int lane = tid & 63;
  const int wv = tid >> 6;
  const int li = lane & 15;
  const int kg = lane >> 4;

  float bv[NT];
#pragma unroll
  for (int t = 0; t < NT; ++t) bv[t] = bias[t * 16 + li];

  for (int tile = blockIdx.x; tile < ntiles; tile += gridDim.x) {
    const int row = tile * 64 + wv * 16 + li;
    const int rowc = (row < nrows) ? row : (nrows - 1);
    const short* xh = Xh + (size_t)rowc * 128;
    const short* xl = Xl + (size_t)rowc * 128;

    f32x4 acc[NT];
#pragma unroll
    for (int t = 0; t < NT; ++t) acc[t] = (f32x4){0.f, 0.f, 0.f, 0.f};

#pragma unroll
    for (int c = 0; c < 4; ++c) {
      const bf16x8 ah = *(const bf16x8*)&xh[c * 32 + kg * 8];
      const bf16x8 al = *(const bf16x8*)&xl[c * 32 + kg * 8];
      const int kb = c * 64 + kg * 16;
#pragma unroll
      for (int t = 0; t < NT; ++t) {
        const int boff = (t * 16 + li) * LDB + kb;
        const bf16x8 bh = *(const bf16x8*)&lds[boff];
        const bf16x8 bl = *(const bf16x8*)&lds[PLANE + boff];
        acc[t] = __builtin_amdgcn_mfma_f32_16x16x32_bf16(al, bh, acc[t], 0, 0, 0);
        acc[t] = __builtin_amdgcn_mfma_f32_16x16x32_bf16(ah, bl, acc[t], 0, 0, 0);
        acc[t] = __builtin_amdgcn_mfma_f32_16x16x32_bf16(ah, bh, acc[t], 0, 0, 0);
      }
    }

    const int orow = tile * 64 + wv * 16 + kg * 4;
#pragma unroll
    for (int t = 0; t < NT; ++t) {
      const int col = t * 16 + li;
#pragma unroll
      for (int r = 0; r < 4; ++r) {
        const int rr = orow + r;
        if (rr < nrows) Y[(size_t)rr * NOUT + col] = acc[t][r] + bv[t];
      }
    }
  }
}

// ---------------- MaxK: radix-select top-16 -> (mask, col-ordered vals) -----
__global__ __launch_bounds__(256) void maxk_kernel(
    const float* __restrict__ T, ulonglong2* __restrict__ Ms,
    float* __restrict__ Vs, int nrows) {
  const int lane = threadIdx.x & 63;
  const int wid = threadIdx.x >> 6;
  const unsigned long long below = ((unsigned long long)1 << lane) - 1;

  for (int row = blockIdx.x * 4 + wid; row < nrows; row += gridDim.x * 4) {
    const float o0 = T[(size_t)row * 128 + lane];
    const float o1 = T[(size_t)row * 128 + 64 + lane];
    const unsigned u0 = __float_as_uint(o0);
    const unsigned u1 = __float_as_uint(o1);
    const unsigned k0 = u0 ^ (((unsigned)((int)u0 >> 31)) | 0x80000000u);
    const unsigned k1 = u1 ^ (((unsigned)((int)u1 >> 31)) | 0x80000000u);

    unsigned P = 0;
    int kth = 16;
#pragma unroll
    for (int b = 31; b >= 0; --b) {
      const unsigned long long ball0 = __ballot(((k0 ^ P) >> b) == 1u);
      const unsigned long long ball1 = __ballot(((k1 ^ P) >> b) == 1u);
      const int c = __popcll(ball0) + __popcll(ball1);
      if (c >= kth)
        P |= (1u << b);
      else
        kth -= c;
    }
    const bool gt0 = k0 > P, gt1 = k1 > P;
    const unsigned long long g0 = __ballot(gt0);
    const unsigned long long g1 = __ballot(gt1);
    const int need = 16 - __popcll(g0) - __popcll(g1);
    const unsigned long long e0 = __ballot(k0 == P);
    const unsigned long long e1 = __ballot(k1 == P);
    const int need1 = need - __popcll(e0);
    const bool s0 = ((e0 >> lane) & 1) && ((int)__popcll(e0 & below) < need);
    const bool s1 = ((e1 >> lane) & 1) && ((int)__popcll(e1 & below) < need1);
    const unsigned long long m0 = __ballot(gt0 || s0);
    const unsigned long long m1 = __ballot(gt1 || s1);

    if (lane == 0) Ms[row] = make_ulonglong2(m0, m1);
    if ((m0 >> lane) & 1)
      Vs[(size_t)row * 16 + __popcll(m0 & below)] = o0;
    if ((m1 >> lane) & 1)
      Vs[(size_t)row * 16 + __popcll(m0) + __popcll(m1 & below)] = o1;
  }
}

// ---------------- CSR build v2: two-level binning ---------------------------
// A: coarse bucket histogram (LDS-staged, ~128K global atomics)
__global__ __launch_bounds__(256) void bhist_kernel(const int* __restrict__ dst,
                                                    int* __restrict__ BC,
                                                    int E) {
  __shared__ int bh[NBUK];
  for (int i = threadIdx.x; i < NBUK; i += 256) bh[i] = 0;
  __syncthreads();
  const int stride = gridDim.x * 256;
  for (int e = blockIdx.x * 256 + threadIdx.x; e < E; e += stride)
    atomicAdd(&bh[dst[e] >> BSHIFT], 1);
  __syncthreads();
  for (int i = threadIdx.x; i < NBUK; i += 256)
    if (bh[i]) atomicAdd(&BC[i], bh[i]);
}

// B: scan bucket counts -> bases/cursors; rs[n]=E
__global__ __launch_bounds__(NBUK) void bscan_kernel(
    const int* __restrict__ BC, int* __restrict__ bases,
    int* __restrict__ bcur, int* __restrict__ rs, int n, int E) {
  __shared__ int sc[NBUK];
  const int t = threadIdx.x;
  const int c = BC[t];
  sc[t] = c;
  __syncthreads();
  for (int st = 1; st < NBUK; st <<= 1) {
    const int v = sc[t];
    const int u = (t >= st) ? sc[t - st] : 0;
    __syncthreads();
    sc[t] = v + u;
    __syncthreads();
  }
  const int excl = sc[t] - c;
  bases[t] = excl;
  bcur[t] = excl;
  if (t == 0) rs[n] = E;
}

// C: bin edges into bucket-major (dst,src) pairs; coalesced copy-out;
//    one global atomic per (block,bucket).
__global__ __launch_bounds__(256) void bin_kernel(
    const int* __restrict__ src, const int* __restrict__ dst,
    int* __restrict__ bcur, uint2* __restrict__ binned, int E, int chunk) {
  __shared__ int cnt[NBUK], off[NBUK], gbase[NBUK];
  __shared__ unsigned short bktof[4096];
  __shared__ uint2 buf[4096];
  const int t = threadIdx.x;
  const int beg = blockIdx.x * chunk;
  const int m = min(chunk, E - beg);  // <= 4096 by construction
  if (m <= 0) return;

  for (int i = t; i < NBUK; i += 256) cnt[i] = 0;
  __syncthreads();

  int d[16], s[16], lp[16], bk[16];
#pragma unroll
  for (int i = 0; i < 16; ++i) {
    const int j = i * 256 + t;
    if (j < m) {
      d[i] = dst[beg + j];
      s[i] = src[beg + j];
      bk[i] = d[i] >> BSHIFT;
      lp[i] = atomicAdd(&cnt[bk[i]], 1);
    } else {
      bk[i] = -1;
    }
  }
  __syncthreads();

  // inclusive scan of cnt into off (2 elems/thread Hillis-Steele)
  for (int i = t; i < NBUK; i += 256) off[i] = cnt[i];
  __syncthreads();
  for (int st = 1; st < NBUK; st <<= 1) {
    int v0, v1, u0, u1;
    {
      const int i0 = t, i1 = t + 256;
      v0 = off[i0]; u0 = (i0 >= st) ? off[i0 - st] : 0;
      v1 = off[i1]; u1 = (i1 >= st) ? off[i1 - st] : 0;
    }
    __syncthreads();
    off[t] = v0 + u0;
    off[t + 256] = v1 + u1;
    __syncthreads();
  }

  // reserve global space per nonzero bucket; fill slot->bucket map
  for (int i = t; i < NBUK; i += 256) {
    const int c = cnt[i];
    if (c > 0) {
      gbase[i] = atomicAdd(&bcur[i], c);
      const int e0 = off[i] - c;
      for (int k = 0; k < c; ++k) bktof[e0 + k] = (unsigned short)i;
    }
  }
  __syncthreads();

  // place pairs into contiguous LDS buffer (bucket-major)
#pragma unroll
  for (int i = 0; i < 16; ++i) {
    if (bk[i] >= 0) {
      buf[(off[bk[i]] - cnt[bk[i]]) + lp[i]] =
          make_uint2((unsigned)d[i], (unsigned)s[i]);
    }
  }
  __syncthreads();

  // coalesced copy-out (runs of same bucket are contiguous in global)
  for (int j = t; j < m; j += 256) {
    const int b = bktof[j];
    const int e0 = off[b] - cnt[b];
    binned[gbase[b] + (j - e0)] = buf[j];
  }
}

// D: per-bucket counting sort -> rs + csr_src (LDS cursors, L2-local writes)
__global__ __launch_bounds__(256) void bbuild_kernel(
    const int* __restrict__ bases, const int* __restrict__ BC,
    const uint2* __restrict__ binned, int* __restrict__ rs,
    int* __restrict__ csr_src, int n) {
  __shared__ int nd[256], sc[256], cur[256];
  const int b = blockIdx.x;
  const int t = threadIdx.x;
  const int base = bases[b];
  const int count = BC[b];
  const int node0 = b << BSHIFT;

  nd[t] = 0;
  __syncthreads();
  for (int i = t; i < count; i += 256)
    atomicAdd(&nd[binned[base + i].x & 255], 1);
  __syncthreads();

  sc[t] = nd[t];
  __syncthreads();
  for (int st = 1; st < 256; st <<= 1) {
    const int v = sc[t];
    const int u = (t >= st) ? sc[t - st] : 0;
    __syncthreads();
    sc[t] = v + u;
    __syncthreads();
  }
  const int excl = sc[t] - nd[t];
  cur[t] = excl;
  if (node0 + t < n) rs[node0 + t] = base + excl;
  __syncthreads();

  for (int i = t; i < count; i += 256) {
    const uint2 p = binned[base + i];
    const int pos = atomicAdd(&cur[p.x & 255], 1);
    csr_src[base + pos] = (int)p.y;
  }
}

// ---------------- Gather (rank-select, no atomics) --------------------------
__global__ __launch_bounds__(256) void gather2_kernel(
    const int* __restrict__ rs, const int* __restrict__ csr_src,
    const ulonglong2* __restrict__ Ms, const float* __restrict__ Vs,
    const float* __restrict__ eps_p, short* __restrict__ Ah,
    short* __restrict__ Al, int nrows) {
  __shared__ __align__(16) float sv[4][16][16];
  __shared__ ulonglong2 sm[4][16];
  const int lane = threadIdx.x & 63;
  const int wid = threadIdx.x >> 6;
  const float e1 = 1.0f + *eps_p;
  const unsigned long long below = ((unsigned long long)1 << lane) - 1;
  const int ee = lane >> 2;
  const int q = lane & 3;

  for (int r = blockIdx.x * 4 + wid; r < nrows; r += gridDim.x * 4) {
    float acc0 = 0.f, acc1 = 0.f;
    const int beg = rs[r], end = rs[r + 1];

    for (int base = beg; base < end; base += 16) {
      const int cnt = min(16, end - base);
      if (ee < cnt) {
        const int s = csr_src[base + ee];
        if (q == 0) sm[wid][ee] = Ms[s];
        const float4 v = *(const float4*)&Vs[(size_t)s * 16 + q * 4];
        *(float4*)&sv[wid][ee][q * 4] = v;
      }
      for (int e = 0; e < cnt; ++e) {
        const ulonglong2 mm = sm[wid][e];
        if ((mm.x >> lane) & 1)
          acc0 += sv[wid][e][__popcll(mm.x & below)];
        if ((mm.y >> lane) & 1)
          acc1 += sv[wid][e][__popcll(mm.x) + __popcll(mm.y & below)];
      }
    }

    {
      const ulonglong2 mr = Ms[r];
      if ((mr.x >> lane) & 1)
        acc0 += e1 * Vs[(size_t)r * 16 + __popcll(mr.x & below)];
      if ((mr.y >> lane) & 1)
        acc1 += e1 * Vs[(size_t)r * 16 + __popcll(mr.x) + __popcll(mr.y & below)];
    }

    const unsigned h0 = rne_bf16(acc0);
    const unsigned h1 = rne_bf16(acc1);
    Ah[(size_t)r * 128 + lane] = (short)h0;
    Ah[(size_t)r * 128 + 64 + lane] = (short)h1;
    Al[(size_t)r * 128 + lane] =
        (short)rne_bf16(acc0 - __uint_as_float(h0 << 16));
    Al[(size_t)r * 128 + 64 + lane] =
        (short)rne_bf16(acc1 - __uint_as_float(h1 << 16));
  }
}

// ---------------------------------------------------------------------------
extern "C" void kernel_launch(void* const* d_in, const int* in_sizes, int n_in,
                              void* d_out, int out_size, void* d_ws,
                              size_t ws_size, hipStream_t stream) {
  const float* x = (const float*)d_in[0];
  const int* src = (const int*)d_in[1];
  const int* dst = (const int*)d_in[2];
  const float* W_in = (const float*)d_in[3];
  const float* b_in = (const float*)d_in[4];
  const float* W_lin = (const float*)d_in[5];
  const float* b_lin = (const float*)d_in[6];
  const float* eps = (const float*)d_in[7];
  const float* W_out = (const float*)d_in[8];
  const float* b_out = (const float*)d_in[9];
  float* out = (float*)d_out;

  const int n = in_sizes[0] / 128;
  const int E = in_sizes[1];

  char* w = (char*)d_ws;
  float* B = (float*)w;               w += (size_t)n * 128 * 4;
  ulonglong2* Ms = (ulonglong2*)w;    w += (size_t)n * 16;
  float* Vs = (float*)w;              w += (size_t)n * 16 * 4;
  int* rs = (int*)w;                  w += (size_t)(n + 1) * 4;
  int* csr_src = (int*)w;             w += (size_t)E * 4;
  uint2* binned = (uint2*)w;          w += (size_t)E * 8;
  int* BC = (int*)w;                  w += NBUK * 4;
  int* bases = (int*)w;               w += NBUK * 4;
  int* bcur = (int*)w;                w += NBUK * 4;
  short* wtAll = (short*)w;           w += (size_t)114688 * 2;
  short* Ah = (short*)w;              w += (size_t)n * 128 * 2;
  short* Al = (short*)w;              w += (size_t)n * 128 * 2;

  short* wtIn = wtAll;
  short* wtL0 = wtAll + 32768;
  short* wtL1 = wtAll + 65536;
  short* wtOut = wtAll + 98304;

  const int gtiles = (n + 63) / 64;
  const int nbuk_eff = (n + 255) >> BSHIFT;
  const int chunk = 4000;
  const int cblocks = (E + chunk - 1) / chunk;
  const dim3 blk(256);

  // ---- CSR build v2 ----
  hipMemsetAsync(BC, 0, NBUK * 4, stream);
  bhist_kernel<<<256, blk, 0, stream>>>(dst, BC, E);
  bscan_kernel<<<1, NBUK, 0, stream>>>(BC, bases, bcur, rs, n, E);
  bin_kernel<<<cblocks, blk, 0, stream>>>(src, dst, bcur, binned, E, chunk);
  bbuild_kernel<<<nbuk_eff, blk, 0, stream>>>(bases, BC, binned, rs, csr_src,
                                              n);

  // ---- weights -> hi/lo bf16 ----
  wt_build_all_kernel<<<(57344 + 255) / 256, blk, 0, stream>>>(W_in, W_lin,
                                                               W_out, wtAll);

  // ---- h = relu(x @ W_in + b_in) -> planes ----
  gemm_in_kernel<<<512, blk, 0, stream>>>(x, wtIn, wtIn + 16384, b_in, Ah, Al,
                                          n, gtiles);

  for (int l = 0; l < 2; ++l) {
    short* wt = l ? wtL1 : wtL0;
    gemm_pl_kernel<128><<<512, blk, 0, stream>>>(
        Ah, Al, wt, wt + 16384, b_lin + (size_t)l * 128, B, n, gtiles);
    maxk_kernel<<<2048, blk, 0, stream>>>(B, Ms, Vs, n);
    gather2_kernel<<<2048, blk, 0, stream>>>(rs, csr_src, Ms, Vs, eps + l, Ah,
                                             Al, n);
  }

  gemm_pl_kernel<64><<<512, blk, 0, stream>>>(Ah, Al, wtOut, wtOut + 8192,
                                              b_out, out, n, gtiles);
}